// Round 1
// baseline (3300.047 us; speedup 1.0000x reference)
//
#include <hip/hip_runtime.h>
#include <math.h>

#define B_ 64
#define T_ 32
#define D_ 128
#define N_ 128
#define SSTR 132   // LDS row stride for 64-row S half-buffer (16B aligned, conflict-free)
#define PSTR 36    // LDS row stride for P (128x32) buffer

__device__ __forceinline__ float softplus_f(float x) {
    return (x > 20.0f) ? x : log1pf(expf(x));
}
__device__ __forceinline__ float sigmoid_f(float x) {
    return 1.0f / (1.0f + expf(-x));
}
__device__ __forceinline__ float wred(float v) {
#pragma unroll
    for (int o = 32; o > 0; o >>= 1) v += __shfl_down(v, o, 64);
    return v;
}
__device__ __forceinline__ void fma4(float* acc, float s, float4 w) {
    acc[0] = fmaf(s, w.x, acc[0]);
    acc[1] = fmaf(s, w.y, acc[1]);
    acc[2] = fmaf(s, w.z, acc[2]);
    acc[3] = fmaf(s, w.w, acc[3]);
}

// Kernel 1 per step: gate vectors (z, r, h, mu) + S_z, S_r column tiles.
// grid (4, 64): blockIdx.x = 32-col tile, blockIdx.y = batch. 256 threads.
__global__ __launch_bounds__(256, 1)
void step_zr(const float* __restrict__ x,
             const float* __restrict__ Uz, const float* __restrict__ Wz,
             const float* __restrict__ Ur, const float* __restrict__ Wr,
             const float* __restrict__ Uh, const float* __restrict__ Wh,
             const float* __restrict__ uzs, const float* __restrict__ wzs,
             const float* __restrict__ urs, const float* __restrict__ wrs,
             float* __restrict__ mu_out, const float* __restrict__ S_out,
             float* __restrict__ wsSz, float* __restrict__ wsSr,
             float* __restrict__ wsVec, int t)
{
    const int b  = blockIdx.y;
    const int j0 = blockIdx.x * 32;
    const int tid = threadIdx.x;

    __shared__ alignas(16) float sS[64 * SSTR];
    __shared__ alignas(16) float sP[128 * PSTR];
    __shared__ alignas(16) float sXt[128];
    __shared__ alignas(16) float sMu[128];
    __shared__ alignas(16) float sZ[128];
    __shared__ alignas(16) float sGz[128];
    __shared__ alignas(16) float sR[128];
    __shared__ alignas(16) float sGr[128];
    __shared__ alignas(16) float sRh[128];
    __shared__ alignas(16) float sH[128];
    __shared__ float sScal[4];   // 0: xx, 1: pp, 2: trS

    const float* Sp = S_out + (size_t)(b * T_ + (t - 1)) * (N_ * N_);  // deref only if t>0
    const float* xt = x + (size_t)(b * T_ + t) * D_;

    // phase 0: stage xt, mu_p
    if (tid < 128) {
        sXt[tid] = xt[tid];
    } else {
        int n = tid - 128;
        sMu[n] = (t > 0) ? mu_out[(size_t)(b * T_ + (t - 1)) * N_ + n] : 0.0f;
    }
    __syncthreads();

    // phase 1: z (waves 0-1), r (waves 2-3)
    {
        const int n = tid & 127;
        const float* Ug = (tid < 128) ? Uz : Ur;
        const float* Wg = (tid < 128) ? Wz : Wr;
        float a = 0.f;
#pragma unroll 4
        for (int d = 0; d < D_; ++d) a = fmaf(sXt[d], Ug[d * N_ + n], a);
#pragma unroll 4
        for (int k = 0; k < N_; ++k) a = fmaf(sMu[k], Wg[k * N_ + n], a);
        float g = sigmoid_f(a);
        if (tid < 128) { sZ[n] = g; sGz[n] = g * (1.f - g); }
        else           { sR[n] = g; sGr[n] = g * (1.f - g); }
    }
    __syncthreads();

    // phase 2: rh (waves 0-1); reductions xx,trS (wave 2), pp (wave 3)
    if (tid < 128) {
        sRh[tid] = sMu[tid] * sR[tid];
    } else if (tid < 192) {
        int l = tid - 128;
        float v = sXt[l] * sXt[l] + sXt[l + 64] * sXt[l + 64];
        v = wred(v);
        float v2 = 0.f;
        if (t > 0) v2 = Sp[l * N_ + l] + Sp[(l + 64) * N_ + (l + 64)];
        v2 = wred(v2);
        if (l == 0) { sScal[0] = v; sScal[2] = v2; }
    } else {
        int l = tid - 192;
        float v = sMu[l] * sMu[l] + sMu[l + 64] * sMu[l + 64];
        v = wred(v);
        if (l == 0) sScal[1] = v;
    }
    __syncthreads();

    // phase 3: h gate (waves 0-1)
    if (tid < 128) {
        const int n = tid;
        float a = 0.f;
#pragma unroll 4
        for (int d = 0; d < D_; ++d) a = fmaf(sXt[d], Uh[d * N_ + n], a);
#pragma unroll 4
        for (int k = 0; k < N_; ++k) a = fmaf(sRh[k], Wh[k * N_ + n], a);
        sH[n] = tanhf(a);
    }
    __syncthreads();

    // phase 4: tile-0 block publishes vectors + mu
    if (blockIdx.x == 0 && tid < 128) {
        const int n = tid;
        float z = sZ[n], h = sH[n];
        float mu = z * sMu[n] + (1.f - z) * h;
        mu_out[(size_t)(b * T_ + t) * N_ + n] = mu;
        float* vb = wsVec + b * 768;
        vb[n]        = z;
        vb[128 + n]  = sR[n];
        vb[256 + n]  = h;
        vb[384 + n]  = 1.f - h * h;
        vb[512 + n]  = sRh[n];
        if (n == 0) vb[640] = sScal[0];
    }

    // matmul phase: S_gate = (W^T S_p W + diag) .* outer(g,g)  for z then r
    const int kq = tid >> 3;  // 0..31
    const int jq = tid & 7;   // 0..7
    const int iq = tid >> 3;

    for (int gate = 0; gate < 2; ++gate) {
        const float* W = gate ? Wr : Wz;

        for (int half = 0; half < 2; ++half) {
            __syncthreads();
            if (t > 0) {
                const float* srcbase = Sp + (size_t)(half * 64) * N_;
#pragma unroll
                for (int i = 0; i < 8; ++i) {
                    int idx4 = tid + i * 256;
                    int kl = idx4 >> 5, l4 = idx4 & 31;
                    float4 v = *(const float4*)(srcbase + kl * N_ + l4 * 4);
                    *(float4*)(&sS[kl * SSTR + l4 * 4]) = v;
                }
            } else {
#pragma unroll
                for (int i = 0; i < 8; ++i) {
                    int idx4 = tid + i * 256;
                    int kl = idx4 >> 5, l4 = idx4 & 31;
                    *(float4*)(&sS[kl * SSTR + l4 * 4]) = make_float4(0.f, 0.f, 0.f, 0.f);
                }
            }
            __syncthreads();

            // mm1: P[k, jtile] = sum_l S[k,l] * W[l, j]
            float acc0[4] = {0.f, 0.f, 0.f, 0.f};
            float acc1[4] = {0.f, 0.f, 0.f, 0.f};
            const float* Wc = W + j0 + jq * 4;
#pragma unroll 2
            for (int l = 0; l < N_; l += 4) {
                float4 w0 = *(const float4*)(Wc + (l + 0) * N_);
                float4 w1 = *(const float4*)(Wc + (l + 1) * N_);
                float4 w2 = *(const float4*)(Wc + (l + 2) * N_);
                float4 w3 = *(const float4*)(Wc + (l + 3) * N_);
                float4 s0 = *(const float4*)(&sS[kq * SSTR + l]);
                float4 s1 = *(const float4*)(&sS[(kq + 32) * SSTR + l]);
                fma4(acc0, s0.x, w0); fma4(acc0, s0.y, w1); fma4(acc0, s0.z, w2); fma4(acc0, s0.w, w3);
                fma4(acc1, s1.x, w0); fma4(acc1, s1.y, w1); fma4(acc1, s1.z, w2); fma4(acc1, s1.w, w3);
            }
            *(float4*)(&sP[(half * 64 + kq) * PSTR + jq * 4])      = make_float4(acc0[0], acc0[1], acc0[2], acc0[3]);
            *(float4*)(&sP[(half * 64 + kq + 32) * PSTR + jq * 4]) = make_float4(acc1[0], acc1[1], acc1[2], acc1[3]);
        }
        __syncthreads();

        // mm2: C[i,j] = sum_k W[k,i] * P[k,j]
        float acc2[4][4] = {{0.f}};
        const float* Wi = W + iq * 4;
#pragma unroll 4
        for (int k = 0; k < N_; ++k) {
            float4 w = *(const float4*)(Wi + k * N_);
            float4 p = *(const float4*)(&sP[k * PSTR + jq * 4]);
            fma4(acc2[0], w.x, p);
            fma4(acc2[1], w.y, p);
            fma4(acc2[2], w.z, p);
            fma4(acc2[3], w.w, p);
        }

        // epilogue: diag terms + outer(g,g), write to workspace
        const float* sGg = gate ? sGr : sGz;
        const float* us  = gate ? urs : uzs;
        const float* wsg = gate ? wrs : wzs;
        float* dst = gate ? wsSr : wsSz;
        float xx = sScal[0];
        float pt = sScal[1] + sScal[2];
#pragma unroll
        for (int ii = 0; ii < 4; ++ii) {
            int i = iq * 4 + ii;
            float gi = sGg[i];
            float o[4];
#pragma unroll
            for (int jj = 0; jj < 4; ++jj) {
                int j = j0 + jq * 4 + jj;
                float v = acc2[ii][jj];
                if (i == j) v += pt * softplus_f(wsg[i]) + xx * softplus_f(us[i]);
                o[jj] = v * gi * sGg[j];
            }
            *(float4*)(&dst[(size_t)b * (N_ * N_) + i * N_ + j0 + jq * 4]) =
                make_float4(o[0], o[1], o[2], o[3]);
        }
        __syncthreads();
    }
}

// Kernel 2 per step: S_g -> S_h -> final S, written to output.
__global__ __launch_bounds__(256, 1)
void step_h(const float* __restrict__ Wh,
            const float* __restrict__ uhs, const float* __restrict__ whs,
            const float* __restrict__ mu_out, float* __restrict__ S_out,
            const float* __restrict__ wsSz, const float* __restrict__ wsSr,
            const float* __restrict__ wsVec, int t)
{
    const int b  = blockIdx.y;
    const int j0 = blockIdx.x * 32;
    const int tid = threadIdx.x;

    __shared__ alignas(16) float sG[64 * SSTR];
    __shared__ alignas(16) float sP[128 * PSTR];
    __shared__ alignas(16) float sMu[128];
    __shared__ alignas(16) float sZ[128];
    __shared__ alignas(16) float sR[128];
    __shared__ alignas(16) float sH[128];
    __shared__ alignas(16) float sGh[128];
    __shared__ float sScal[4];   // 0: rr, 1: trg, 2: xx

    const float* Sp = S_out + (size_t)(b * T_ + (t - 1)) * (N_ * N_);  // deref only if t>0
    const float* Sr = wsSr + (size_t)b * (N_ * N_);
    const float* Sz = wsSz + (size_t)b * (N_ * N_);
    const float* vb = wsVec + b * 768;

    if (tid < 128) {
        sZ[tid]  = vb[tid];
        sR[tid]  = vb[128 + tid];
        sH[tid]  = vb[256 + tid];
        sGh[tid] = vb[384 + tid];
        sMu[tid] = (t > 0) ? mu_out[(size_t)(b * T_ + (t - 1)) * N_ + tid] : 0.f;
    }
    __syncthreads();

    // reductions: rr (wave 0), trg (wave 1), xx fetch (thread 128)
    if (tid < 64) {
        float r1 = vb[512 + tid], r2 = vb[512 + tid + 64];
        float v = wred(r1 * r1 + r2 * r2);
        if (tid == 0) sScal[0] = v;
    } else if (tid < 128) {
        int l = tid - 64;
        float v = 0.f;
#pragma unroll
        for (int q = 0; q < 2; ++q) {
            int k = l + q * 64;
            float spd = (t > 0) ? Sp[k * N_ + k] : 0.f;
            float srd = Sr[k * N_ + k];
            v += spd * srd + sMu[k] * sMu[k] * srd + sR[k] * sR[k] * spd;
        }
        v = wred(v);
        if (l == 0) sScal[1] = v;
    } else if (tid == 128) {
        sScal[2] = vb[640];
    }

    const int kq = tid >> 3, jq = tid & 7, iq = tid >> 3;

    for (int half = 0; half < 2; ++half) {
        __syncthreads();
        // stage S_g rows: S_g = S_p.*S_r + outer(mu,mu).*S_r + outer(r,r).*S_p
#pragma unroll
        for (int i = 0; i < 8; ++i) {
            int idx4 = tid + i * 256;
            int kl = idx4 >> 5, l4 = idx4 & 31;
            int k = half * 64 + kl;
            float4 sp4 = (t > 0) ? *(const float4*)(Sp + k * N_ + l4 * 4)
                                 : make_float4(0.f, 0.f, 0.f, 0.f);
            float4 sr4 = *(const float4*)(Sr + k * N_ + l4 * 4);
            float muk = sMu[k], rk = sR[k];
            float4 mul4 = *(const float4*)(&sMu[l4 * 4]);
            float4 rl4  = *(const float4*)(&sR[l4 * 4]);
            float4 g;
            g.x = sp4.x * sr4.x + muk * mul4.x * sr4.x + rk * rl4.x * sp4.x;
            g.y = sp4.y * sr4.y + muk * mul4.y * sr4.y + rk * rl4.y * sp4.y;
            g.z = sp4.z * sr4.z + muk * mul4.z * sr4.z + rk * rl4.z * sp4.z;
            g.w = sp4.w * sr4.w + muk * mul4.w * sr4.w + rk * rl4.w * sp4.w;
            *(float4*)(&sG[kl * SSTR + l4 * 4]) = g;
        }
        __syncthreads();

        float acc0[4] = {0.f, 0.f, 0.f, 0.f};
        float acc1[4] = {0.f, 0.f, 0.f, 0.f};
        const float* Wc = Wh + j0 + jq * 4;
#pragma unroll 2
        for (int l = 0; l < N_; l += 4) {
            float4 w0 = *(const float4*)(Wc + (l + 0) * N_);
            float4 w1 = *(const float4*)(Wc + (l + 1) * N_);
            float4 w2 = *(const float4*)(Wc + (l + 2) * N_);
            float4 w3 = *(const float4*)(Wc + (l + 3) * N_);
            float4 s0 = *(const float4*)(&sG[kq * SSTR + l]);
            float4 s1 = *(const float4*)(&sG[(kq + 32) * SSTR + l]);
            fma4(acc0, s0.x, w0); fma4(acc0, s0.y, w1); fma4(acc0, s0.z, w2); fma4(acc0, s0.w, w3);
            fma4(acc1, s1.x, w0); fma4(acc1, s1.y, w1); fma4(acc1, s1.z, w2); fma4(acc1, s1.w, w3);
        }
        *(float4*)(&sP[(half * 64 + kq) * PSTR + jq * 4])      = make_float4(acc0[0], acc0[1], acc0[2], acc0[3]);
        *(float4*)(&sP[(half * 64 + kq + 32) * PSTR + jq * 4]) = make_float4(acc1[0], acc1[1], acc1[2], acc1[3]);
    }
    __syncthreads();

    // mm2: S_hh tile
    float acc2[4][4] = {{0.f}};
    const float* Wi = Wh + iq * 4;
#pragma unroll 4
    for (int k = 0; k < N_; ++k) {
        float4 w = *(const float4*)(Wi + k * N_);
        float4 p = *(const float4*)(&sP[k * PSTR + jq * 4]);
        fma4(acc2[0], w.x, p);
        fma4(acc2[1], w.y, p);
        fma4(acc2[2], w.z, p);
        fma4(acc2[3], w.w, p);
    }

    float coef = sScal[0] + sScal[1];   // rr + trg
    float xx   = sScal[2];
    float* outS = S_out + (size_t)(b * T_ + t) * (N_ * N_);

#pragma unroll
    for (int ii = 0; ii < 4; ++ii) {
        int i = iq * 4 + ii;
        float4 sz4 = *(const float4*)(Sz + i * N_ + j0 + jq * 4);
        float4 sp4 = (t > 0) ? *(const float4*)(Sp + i * N_ + j0 + jq * 4)
                             : make_float4(0.f, 0.f, 0.f, 0.f);
        float szv[4] = {sz4.x, sz4.y, sz4.z, sz4.w};
        float spv[4] = {sp4.x, sp4.y, sp4.z, sp4.w};
        float zi = sZ[i], ghi = sGh[i], dmi = sMu[i] - sH[i];
        float o[4];
#pragma unroll
        for (int jj = 0; jj < 4; ++jj) {
            int j = j0 + jq * 4 + jj;
            float shh = acc2[ii][jj];
            if (i == j) shh += coef * softplus_f(whs[i]) + xx * softplus_f(uhs[i]);
            float sh = shh * ghi * sGh[j];
            float zj = sZ[j];
            float s = szv[jj] * (spv[jj] + sh + dmi * (sMu[j] - sH[j]))
                    + zi * zj * spv[jj]
                    + (1.f - zi) * (1.f - zj) * sh;
            if (!isfinite(s)) s = 0.f;
            if (i == j) s = fabsf(s);
            o[jj] = s;
        }
        *(float4*)(outS + i * N_ + j0 + jq * 4) = make_float4(o[0], o[1], o[2], o[3]);
    }
}

extern "C" void kernel_launch(void* const* d_in, const int* in_sizes, int n_in,
                              void* d_out, int out_size, void* d_ws, size_t ws_size,
                              hipStream_t stream)
{
    (void)in_sizes; (void)n_in; (void)out_size; (void)ws_size;
    const float* x   = (const float*)d_in[0];
    const float* Uz  = (const float*)d_in[1];
    const float* Wz  = (const float*)d_in[2];
    const float* Ur  = (const float*)d_in[3];
    const float* Wr  = (const float*)d_in[4];
    const float* Uh  = (const float*)d_in[5];
    const float* Wh  = (const float*)d_in[6];
    const float* uzs = (const float*)d_in[7];
    const float* wzs = (const float*)d_in[8];
    const float* urs = (const float*)d_in[9];
    const float* wrs = (const float*)d_in[10];
    const float* uhs = (const float*)d_in[11];
    const float* whs = (const float*)d_in[12];

    float* mu_out = (float*)d_out;
    float* S_out  = (float*)d_out + (size_t)B_ * T_ * N_;

    float* wsSz  = (float*)d_ws;
    float* wsSr  = wsSz + (size_t)B_ * N_ * N_;
    float* wsVec = wsSr + (size_t)B_ * N_ * N_;

    dim3 grid(4, B_), blk(256);
    for (int t = 0; t < T_; ++t) {
        hipLaunchKernelGGL(step_zr, grid, blk, 0, stream,
                           x, Uz, Wz, Ur, Wr, Uh, Wh,
                           uzs, wzs, urs, wrs,
                           mu_out, S_out, wsSz, wsSr, wsVec, t);
        hipLaunchKernelGGL(step_h, grid, blk, 0, stream,
                           Wh, uhs, whs, mu_out, S_out,
                           wsSz, wsSr, wsVec, t);
    }
}

// Round 2
// 1681.389 us; speedup vs baseline: 1.9627x; 1.9627x over previous
//
#include <hip/hip_runtime.h>
#include <math.h>

#define B_ 64
#define T_ 32
#define D_ 128
#define N_ 128
#define SBS 72      // ushort stride of S-split rows (64 cols + 8 pad), 144 B (16B-aligned)
#define PTS 136     // ushort stride of PT rows (128 cols + 8 pad), 272 B (16B-aligned)

typedef __attribute__((ext_vector_type(8))) short s8v;
typedef __attribute__((ext_vector_type(4))) float f4;

__device__ __forceinline__ float softplus_f(float v){ return (v > 20.f) ? v : log1pf(expf(v)); }
__device__ __forceinline__ float sigmoid_f(float v){ return 1.f / (1.f + expf(-v)); }
__device__ __forceinline__ float wred(float v){
#pragma unroll
    for (int o = 32; o > 0; o >>= 1) v += __shfl_down(v, o, 64);
    return v;
}
// fp32 -> bf16 hi (RN) + bf16 lo (RN of remainder): covers ~16 mantissa bits.
__device__ __forceinline__ void split2(float v, unsigned short& h, unsigned short& l){
    unsigned int u  = __float_as_uint(v);
    unsigned int rh = u + 0x7fffu + ((u >> 16) & 1u);
    h = (unsigned short)(rh >> 16);
    float fh = __uint_as_float(rh & 0xffff0000u);
    float lo = v - fh;
    unsigned int ul = __float_as_uint(lo);
    unsigned int rl = ul + 0x7fffu + ((ul >> 16) & 1u);
    l = (unsigned short)(rl >> 16);
}
__device__ __forceinline__ void split4_store(float4 v, unsigned short* hp, unsigned short* lp){
    unsigned short h0,h1,h2,h3,l0,l1,l2,l3;
    split2(v.x,h0,l0); split2(v.y,h1,l1); split2(v.z,h2,l2); split2(v.w,h3,l3);
    uint2 H = make_uint2((unsigned)h0 | ((unsigned)h1 << 16), (unsigned)h2 | ((unsigned)h3 << 16));
    uint2 L = make_uint2((unsigned)l0 | ((unsigned)l1 << 16), (unsigned)l2 | ((unsigned)l3 << 16));
    *(uint2*)hp = H; *(uint2*)lp = L;
}
__device__ __forceinline__ f4 mfma3(s8v ah, s8v al, s8v bh, s8v bl, f4 c){
    c = __builtin_amdgcn_mfma_f32_16x16x32_bf16(ah, bh, c, 0, 0, 0);
    c = __builtin_amdgcn_mfma_f32_16x16x32_bf16(ah, bl, c, 0, 0, 0);
    c = __builtin_amdgcn_mfma_f32_16x16x32_bf16(al, bh, c, 0, 0, 0);
    return c;
}

// ---- prep: split+transpose W into WT[n][l] bf16 hi/lo (n-major, l contiguous) ----
__global__ __launch_bounds__(256)
void prep_w(const float* __restrict__ Wz, const float* __restrict__ Wr,
            const float* __restrict__ Wh, unsigned short* __restrict__ WT){
    int gate = blockIdx.x, n0 = blockIdx.y * 16, tid = threadIdx.x;
    const float* W = (gate == 0) ? Wz : (gate == 1) ? Wr : Wh;
    unsigned short* hi = WT + (size_t)gate * 32768;
    unsigned short* lo = hi + 16384;
#pragma unroll
    for (int e = 0; e < 8; ++e){
        int idx = tid + e * 256;
        int n = n0 + (idx >> 7), k = idx & 127;
        float v = W[(size_t)k * 128 + n];
        unsigned short h, l; split2(v, h, l);
        hi[(size_t)n * 128 + k] = h;
        lo[(size_t)n * 128 + k] = l;
    }
}

// ---- prep: XU[g][bt][n] = x_bt . U_g  (g: 0=z,1=r,2=h), XX[bt] = ||x_bt||^2 ----
__global__ __launch_bounds__(256)
void prep_xu(const float* __restrict__ x, const float* __restrict__ Uz,
             const float* __restrict__ Ur, const float* __restrict__ Uh,
             float* __restrict__ XU, float* __restrict__ XX){
    int bt = blockIdx.x, tid = threadIdx.x;
    __shared__ float sX[128];
    __shared__ float sRed[256];
    __shared__ float sP[4];
    if (tid < 128) sX[tid] = x[(size_t)bt * 128 + tid];
    __syncthreads();
    {
        float v = (tid < 128) ? sX[tid] * sX[tid] : 0.f;
        v = wred(v);
        if ((tid & 63) == 0) sP[tid >> 6] = v;
    }
    const float* Us[3] = {Uz, Ur, Uh};
#pragma unroll 1
    for (int g = 0; g < 3; ++g){
        int n = tid & 127, hf = tid >> 7;
        float p = 0.f;
#pragma unroll 8
        for (int k = hf * 64; k < hf * 64 + 64; ++k) p = fmaf(sX[k], Us[g][(size_t)k * 128 + n], p);
        sRed[tid] = p;
        __syncthreads();
        if (tid < 128) XU[(size_t)g * (2048 * 128) + (size_t)bt * 128 + tid] = sRed[tid] + sRed[tid + 128];
        __syncthreads();
    }
    if (tid == 0) XX[bt] = sP[0] + sP[1] + sP[2] + sP[3];
}

// ---- per-step kernel 1: gates + S_z, S_r via bf16x3 MFMA sandwiches ----
__global__ __launch_bounds__(256, 1)
void step_zr(const float* __restrict__ Wz, const float* __restrict__ Wr, const float* __restrict__ Wh,
             const float* __restrict__ uzs, const float* __restrict__ wzs,
             const float* __restrict__ urs, const float* __restrict__ wrs,
             const unsigned short* __restrict__ WT,
             const float* __restrict__ XU, const float* __restrict__ XX,
             float* __restrict__ mu_out, const float* __restrict__ S_out,
             float* __restrict__ wsSz, float* __restrict__ wsSr,
             float* __restrict__ wsVec, int t)
{
    const int b = blockIdx.y, j0 = blockIdx.x * 32, tid = threadIdx.x;
    const int lane = tid & 63, w = tid >> 6, q = (tid >> 4) & 3, lm = tid & 15;

    __shared__ alignas(16) char sBig[36864];
    unsigned short* sShi = (unsigned short*)sBig;
    unsigned short* sSlo = (unsigned short*)(sBig + 128 * SBS * 2);
    unsigned short* sPT  = (unsigned short*)sBig;   // reused after mm1: 4 planes of 32*PTS

    __shared__ float sMu[128], sZ[128], sGz[128], sR[128], sGr[128], sRh[128];
    __shared__ float sSP[4][128];                    // softplus(uz), (wz), (ur), (wr)
    __shared__ float sRed[256];
    __shared__ float sScalA[4], sScalB[4], sScalC[4];

    const int bt = b * T_ + t;
    const float* Sp = (t > 0) ? (S_out + (size_t)(bt - 1) * 16384) : S_out;

    // P0: mu_p + softplus tables
    if (tid < 128) sMu[tid] = (t > 0) ? mu_out[(size_t)(bt - 1) * 128 + tid] : 0.f;
    for (int a = tid; a < 512; a += 256){
        int tb = a >> 7, n = a & 127;
        const float* src = (tb == 0) ? uzs : (tb == 1) ? wzs : (tb == 2) ? urs : wrs;
        sSP[tb][n] = softplus_f(src[n]);
    }
    __syncthreads();

    // P1: z (waves 0-1) and r (waves 2-3)
    {
        int g = tid >> 7, n = tid & 127;
        const float* Wg = g ? Wr : Wz;
        float a = XU[(size_t)g * (2048 * 128) + (size_t)bt * 128 + n];
#pragma unroll 16
        for (int k = 0; k < 128; ++k) a = fmaf(sMu[k], Wg[(size_t)k * 128 + n], a);
        float gg = sigmoid_f(a);
        if (!g){ sZ[n] = gg; sGz[n] = gg * (1.f - gg); }
        else   { sR[n] = gg; sGr[n] = gg * (1.f - gg); }
    }
    __syncthreads();

    // P2: rh, pp, trS
    if (tid < 128) sRh[tid] = sMu[tid] * sR[tid];
    {
        float v1 = (tid < 128) ? sMu[tid] * sMu[tid] : 0.f;
        float v2 = (tid < 128 && t > 0) ? Sp[(size_t)tid * 129] : 0.f;
        v1 = wred(v1); v2 = wred(v2);
        if (lane == 0){ sScalA[w] = v1; sScalB[w] = v2; }
    }
    __syncthreads();

    // P3: h matvec (split-K) + rr
    {
        int n = tid & 127, hf = tid >> 7;
        float p = 0.f;
#pragma unroll 16
        for (int k = hf * 64; k < hf * 64 + 64; ++k) p = fmaf(sRh[k], Wh[(size_t)k * 128 + n], p);
        sRed[tid] = p;
        float v = (tid < 128) ? sRh[tid] * sRh[tid] : 0.f;
        v = wred(v);
        if (lane == 0) sScalC[w] = v;
    }
    __syncthreads();

    // P4: h, mu, publish (jtile-0 block only)
    if (tid < 128){
        float ah = XU[(size_t)2 * (2048 * 128) + (size_t)bt * 128 + tid] + sRed[tid] + sRed[tid + 128];
        float h = tanhf(ah);
        float z = sZ[tid];
        if (blockIdx.x == 0){
            mu_out[(size_t)bt * 128 + tid] = z * sMu[tid] + (1.f - z) * h;
            float* vbp = wsVec + (size_t)b * 520;
            vbp[tid] = z; vbp[128 + tid] = sR[tid]; vbp[256 + tid] = h; vbp[384 + tid] = 1.f - h * h;
            if (tid == 0) vbp[512] = sScalC[0] + sScalC[1] + sScalC[2] + sScalC[3];
        }
    }

    // mm1: P_g = S_p . W_g[:, jtile]  (accumulated over 2 l-halves)
    f4 accP[8];
#pragma unroll
    for (int i = 0; i < 8; ++i) accP[i] = (f4){0.f, 0.f, 0.f, 0.f};

    for (int half = 0; half < 2; ++half){
        __syncthreads();
        {
            int l0g = half * 64;
#pragma unroll
            for (int i = 0; i < 8; ++i){
                int idx4 = tid + i * 256;
                int row = idx4 >> 4, c4 = idx4 & 15;
                float4 v = make_float4(0.f, 0.f, 0.f, 0.f);
                if (t > 0) v = *(const float4*)(Sp + (size_t)row * 128 + l0g + c4 * 4);
                split4_store(v, &sShi[row * SBS + c4 * 4], &sSlo[row * SBS + c4 * 4]);
            }
        }
        __syncthreads();
#pragma unroll
        for (int c = 0; c < 2; ++c){
            int lloc = c * 32 + q * 8;
            int lglob = half * 64 + lloc;
            s8v aH[2], aL[2];
#pragma unroll
            for (int s = 0; s < 2; ++s){
                int row = (w * 2 + s) * 16 + lm;
                aH[s] = *(const s8v*)&sShi[row * SBS + lloc];
                aL[s] = *(const s8v*)&sSlo[row * SBS + lloc];
            }
#pragma unroll
            for (int nt = 0; nt < 2; ++nt){
                size_t off = (size_t)(j0 + nt * 16 + lm) * 128 + lglob;
                s8v bzH = *(const s8v*)&WT[off];
                s8v bzL = *(const s8v*)&WT[16384 + off];
                s8v brH = *(const s8v*)&WT[32768 + off];
                s8v brL = *(const s8v*)&WT[49152 + off];
#pragma unroll
                for (int s = 0; s < 2; ++s){
                    accP[s * 2 + nt]     = mfma3(aH[s], aL[s], bzH, bzL, accP[s * 2 + nt]);
                    accP[4 + s * 2 + nt] = mfma3(aH[s], aL[s], brH, brL, accP[4 + s * 2 + nt]);
                }
            }
        }
    }
    __syncthreads();   // sS dead; overlay PT

    // store P transposed (PT[j][k]) split hi/lo: planes z-hi, z-lo, r-hi, r-lo
#pragma unroll
    for (int g = 0; g < 2; ++g)
#pragma unroll
        for (int s = 0; s < 2; ++s)
#pragma unroll
            for (int nt = 0; nt < 2; ++nt){
                f4 a = accP[g * 4 + s * 2 + nt];
                int kb = (w * 2 + s) * 16 + q * 4;
                int jr = nt * 16 + lm;
                split4_store(make_float4(a[0], a[1], a[2], a[3]),
                             &sPT[(g * 2 + 0) * (32 * PTS) + jr * PTS + kb],
                             &sPT[(g * 2 + 1) * (32 * PTS) + jr * PTS + kb]);
            }
    __syncthreads();

    // mm2 + epilogue per gate: C = W^T P ; S_gate = (C + diag) .* outer(gg,gg)
    float pp  = sScalA[0] + sScalA[1] + sScalA[2] + sScalA[3];
    float trS = sScalB[0] + sScalB[1] + sScalB[2] + sScalB[3];
    float pt  = pp + trS;
    float xxv = XX[bt];

#pragma unroll 1
    for (int g = 0; g < 2; ++g){
        const unsigned short* AH = WT + (size_t)g * 32768;
        const unsigned short* AL = AH + 16384;
        const unsigned short* PH = sPT + (g * 2) * (32 * PTS);
        const unsigned short* PL = PH + (32 * PTS);
        f4 acc[4];
#pragma unroll
        for (int i = 0; i < 4; ++i) acc[i] = (f4){0.f, 0.f, 0.f, 0.f};
#pragma unroll
        for (int c = 0; c < 4; ++c){
            int k0 = c * 32 + q * 8;
            s8v aH[2], aL[2];
#pragma unroll
            for (int s = 0; s < 2; ++s){
                size_t row = (size_t)((w * 2 + s) * 16 + lm) * 128 + k0;
                aH[s] = *(const s8v*)&AH[row];
                aL[s] = *(const s8v*)&AL[row];
            }
#pragma unroll
            for (int nt = 0; nt < 2; ++nt){
                int jj = (nt * 16 + lm) * PTS + k0;
                s8v bH = *(const s8v*)&PH[jj];
                s8v bL = *(const s8v*)&PL[jj];
#pragma unroll
                for (int s = 0; s < 2; ++s)
                    acc[s * 2 + nt] = mfma3(aH[s], aL[s], bH, bL, acc[s * 2 + nt]);
            }
        }
        const float* G   = g ? sGr : sGz;
        const float* spU = g ? sSP[2] : sSP[0];
        const float* spW = g ? sSP[3] : sSP[1];
        float* dst = (g ? wsSr : wsSz) + (size_t)b * 16384;
#pragma unroll
        for (int s = 0; s < 2; ++s)
#pragma unroll
            for (int nt = 0; nt < 2; ++nt){
                f4 a = acc[s * 2 + nt];
                int ib = (w * 2 + s) * 16 + q * 4;
                int j = j0 + nt * 16 + lm;
                float gj = G[j];
#pragma unroll
                for (int r = 0; r < 4; ++r){
                    int i = ib + r;
                    float v = a[r];
                    if (i == j) v += pt * spW[i] + xxv * spU[i];
                    dst[(size_t)i * 128 + j] = v * G[i] * gj;
                }
            }
    }
}

// ---- per-step kernel 2: S_g build + h-sandwich + final S ----
__global__ __launch_bounds__(256, 1)
void step_h(const float* __restrict__ uhs, const float* __restrict__ whs,
            const unsigned short* __restrict__ WT,
            const float* __restrict__ XX,
            const float* __restrict__ mu_out, float* __restrict__ S_out,
            const float* __restrict__ wsSz, const float* __restrict__ wsSr,
            const float* __restrict__ wsVec, int t)
{
    const int b = blockIdx.y, j0 = blockIdx.x * 32, tid = threadIdx.x;
    const int lane = tid & 63, w = tid >> 6, q = (tid >> 4) & 3, lm = tid & 15;

    __shared__ alignas(16) char sBig[36864];
    unsigned short* sGhi = (unsigned short*)sBig;
    unsigned short* sGlo = (unsigned short*)(sBig + 128 * SBS * 2);
    unsigned short* sPT  = (unsigned short*)sBig;

    __shared__ float sMu[128], sZ[128], sR[128], sH[128], sGh[128];
    __shared__ float sSPu[128], sSPw[128];
    __shared__ float sScal[4];

    const int bt = b * T_ + t;
    const float* Sp = (t > 0) ? (S_out + (size_t)(bt - 1) * 16384) : S_out;
    const float* Sr = wsSr + (size_t)b * 16384;
    const float* vb = wsVec + (size_t)b * 520;
    const unsigned short* WTH = WT + 65536;
    const unsigned short* WTL = WT + 81920;

    if (tid < 128){
        sZ[tid] = vb[tid]; sR[tid] = vb[128 + tid]; sH[tid] = vb[256 + tid]; sGh[tid] = vb[384 + tid];
        sMu[tid] = (t > 0) ? mu_out[(size_t)(bt - 1) * 128 + tid] : 0.f;
        sSPu[tid] = softplus_f(uhs[tid]); sSPw[tid] = softplus_f(whs[tid]);
    }

    f4 accP[4];
#pragma unroll
    for (int i = 0; i < 4; ++i) accP[i] = (f4){0.f, 0.f, 0.f, 0.f};
    float tdiag = 0.f;

    for (int half = 0; half < 2; ++half){
        __syncthreads();
        {
            int l0g = half * 64;
#pragma unroll
            for (int i = 0; i < 8; ++i){
                int idx4 = tid + i * 256;
                int row = idx4 >> 4, c4 = idx4 & 15;
                int colg = l0g + c4 * 4;
                float4 sp4 = make_float4(0.f, 0.f, 0.f, 0.f);
                if (t > 0) sp4 = *(const float4*)(Sp + (size_t)row * 128 + colg);
                float4 sr4 = *(const float4*)(Sr + (size_t)row * 128 + colg);
                float muk = sMu[row], rk = sR[row];
                float4 mc = *(const float4*)&sMu[colg];
                float4 rc = *(const float4*)&sR[colg];
                float4 gv;
                gv.x = sp4.x * sr4.x + muk * mc.x * sr4.x + rk * rc.x * sp4.x;
                gv.y = sp4.y * sr4.y + muk * mc.y * sr4.y + rk * rc.y * sp4.y;
                gv.z = sp4.z * sr4.z + muk * mc.z * sr4.z + rk * rc.z * sp4.z;
                gv.w = sp4.w * sr4.w + muk * mc.w * sr4.w + rk * rc.w * sp4.w;
                int d = row - colg;
                if (d >= 0 && d < 4) tdiag += (d == 0) ? gv.x : (d == 1) ? gv.y : (d == 2) ? gv.z : gv.w;
                split4_store(gv, &sGhi[row * SBS + c4 * 4], &sGlo[row * SBS + c4 * 4]);
            }
        }
        __syncthreads();
#pragma unroll
        for (int c = 0; c < 2; ++c){
            int lloc = c * 32 + q * 8;
            int lglob = half * 64 + lloc;
            s8v aH[2], aL[2];
#pragma unroll
            for (int s = 0; s < 2; ++s){
                int row = (w * 2 + s) * 16 + lm;
                aH[s] = *(const s8v*)&sGhi[row * SBS + lloc];
                aL[s] = *(const s8v*)&sGlo[row * SBS + lloc];
            }
#pragma unroll
            for (int nt = 0; nt < 2; ++nt){
                size_t off = (size_t)(j0 + nt * 16 + lm) * 128 + lglob;
                s8v bH = *(const s8v*)&WTH[off];
                s8v bL = *(const s8v*)&WTL[off];
#pragma unroll
                for (int s = 0; s < 2; ++s)
                    accP[s * 2 + nt] = mfma3(aH[s], aL[s], bH, bL, accP[s * 2 + nt]);
            }
        }
    }
    float td = wred(tdiag);
    __syncthreads();   // sG dead; overlay PT
    if (lane == 0) sScal[w] = td;
#pragma unroll
    for (int s = 0; s < 2; ++s)
#pragma unroll
        for (int nt = 0; nt < 2; ++nt){
            f4 a = accP[s * 2 + nt];
            int kb = (w * 2 + s) * 16 + q * 4;
            int jr = nt * 16 + lm;
            split4_store(make_float4(a[0], a[1], a[2], a[3]),
                         &sPT[jr * PTS + kb],
                         &sPT[(32 * PTS) + jr * PTS + kb]);
        }
    __syncthreads();

    // mm2: C = Wh^T P
    f4 acc[4];
#pragma unroll
    for (int i = 0; i < 4; ++i) acc[i] = (f4){0.f, 0.f, 0.f, 0.f};
#pragma unroll
    for (int c = 0; c < 4; ++c){
        int k0 = c * 32 + q * 8;
        s8v aH[2], aL[2];
#pragma unroll
        for (int s = 0; s < 2; ++s){
            size_t row = (size_t)((w * 2 + s) * 16 + lm) * 128 + k0;
            aH[s] = *(const s8v*)&WTH[row];
            aL[s] = *(const s8v*)&WTL[row];
        }
#pragma unroll
        for (int nt = 0; nt < 2; ++nt){
            int jj = (nt * 16 + lm) * PTS + k0;
            s8v bH = *(const s8v*)&sPT[jj];
            s8v bL = *(const s8v*)&sPT[(32 * PTS) + jj];
#pragma unroll
            for (int s = 0; s < 2; ++s)
                acc[s * 2 + nt] = mfma3(aH[s], aL[s], bH, bL, acc[s * 2 + nt]);
        }
    }

    // epilogue: S_h + final combine
    float trg  = sScal[0] + sScal[1] + sScal[2] + sScal[3];
    float coef = vb[512] + trg;           // rr + trg
    float xxv  = XX[bt];
    const float* Szb = wsSz + (size_t)b * 16384;
    float* outS = S_out + (size_t)bt * 16384;
#pragma unroll
    for (int s = 0; s < 2; ++s)
#pragma unroll
        for (int nt = 0; nt < 2; ++nt){
            f4 a = acc[s * 2 + nt];
            int ib = (w * 2 + s) * 16 + q * 4;
            int j = j0 + nt * 16 + lm;
            float zj = sZ[j], ghj = sGh[j];
#pragma unroll
            for (int r = 0; r < 4; ++r){
                int i = ib + r;
                float shh = a[r];
                if (i == j) shh += coef * sSPw[i] + xxv * sSPu[i];
                float sh = shh * sGh[i] * ghj;
                float szv = Szb[(size_t)i * 128 + j];
                float spv = (t > 0) ? Sp[(size_t)i * 128 + j] : 0.f;
                float dmi = sMu[i] - sH[i], dmj = sMu[j] - sH[j];
                float zi = sZ[i];
                float sv = szv * (spv + sh + dmi * dmj) + zi * zj * spv + (1.f - zi) * (1.f - zj) * sh;
                if (!isfinite(sv)) sv = 0.f;
                if (i == j) sv = fabsf(sv);
                outS[(size_t)i * 128 + j] = sv;
            }
        }
}

extern "C" void kernel_launch(void* const* d_in, const int* in_sizes, int n_in,
                              void* d_out, int out_size, void* d_ws, size_t ws_size,
                              hipStream_t stream)
{
    (void)in_sizes; (void)n_in; (void)out_size; (void)ws_size;
    const float* x   = (const float*)d_in[0];
    const float* Uz  = (const float*)d_in[1];
    const float* Wz  = (const float*)d_in[2];
    const float* Ur  = (const float*)d_in[3];
    const float* Wr  = (const float*)d_in[4];
    const float* Uh  = (const float*)d_in[5];
    const float* Wh  = (const float*)d_in[6];
    const float* uzs = (const float*)d_in[7];
    const float* wzs = (const float*)d_in[8];
    const float* urs = (const float*)d_in[9];
    const float* wrs = (const float*)d_in[10];
    const float* uhs = (const float*)d_in[11];
    const float* whs = (const float*)d_in[12];

    float* mu_out = (float*)d_out;
    float* S_out  = (float*)d_out + (size_t)B_ * T_ * N_;

    char* ws = (char*)d_ws;
    unsigned short* wsWT = (unsigned short*)ws;                 // 6 planes x 16384 ushort
    float* wsXU  = (float*)(ws + 196608);                       // 3 x 2048 x 128
    float* wsXX  = (float*)(ws + 3342336);                      // 2048
    float* wsSz  = (float*)(ws + 3350528);                      // 64 x 16384
    float* wsSr  = (float*)(ws + 7544832);                      // 64 x 16384
    float* wsVec = (float*)(ws + 11739136);                     // 64 x 520

    hipLaunchKernelGGL(prep_w, dim3(3, 8), dim3(256), 0, stream, Wz, Wr, Wh, wsWT);
    hipLaunchKernelGGL(prep_xu, dim3(2048), dim3(256), 0, stream, x, Uz, Ur, Uh, wsXU, wsXX);

    dim3 grid(4, B_), blk(256);
    for (int t = 0; t < T_; ++t){
        hipLaunchKernelGGL(step_zr, grid, blk, 0, stream,
                           Wz, Wr, Wh, uzs, wzs, urs, wrs,
                           wsWT, wsXU, wsXX, mu_out, S_out, wsSz, wsSr, wsVec, t);
        hipLaunchKernelGGL(step_h, grid, blk, 0, stream,
                           uhs, whs, wsWT, wsXX, mu_out, S_out, wsSz, wsSr, wsVec, t);
    }
}